// Round 1
// baseline (1236.503 us; speedup 1.0000x reference)
//
#include <hip/hip_runtime.h>

// Problem constants (from reference setup_inputs)
#define NN 50000
#define EE 1600000
#define CC 128
#define HH 8
#define TOT (EE + NN)   // 1,650,000 rows in output

// ---- monotone float<->uint mapping for atomicMax on floats ----
__device__ inline unsigned fflip(float f) {
    unsigned u = __float_as_uint(f);
    return (u & 0x80000000u) ? ~u : (u | 0x80000000u);
}
__device__ inline float funflip(unsigned u) {
    unsigned b = (u & 0x80000000u) ? (u ^ 0x80000000u) : ~u;
    return __uint_as_float(b);
}

// ---- kernel 0: init m = flip(-inf), s = 0 ----
__global__ void k_init(unsigned* __restrict__ m, float* __restrict__ s, int n) {
    int i = blockIdx.x * blockDim.x + threadIdx.x;
    if (i < n) { m[i] = 0x007FFFFFu; s[i] = 0.0f; }  // 0x007FFFFF == fflip(-inf)
}

// ---- kernel 1: y1 = x @ W[:C], y2 = x @ W[C:]  (N x 8 each) ----
// 16 threads per node: thread j<8 -> y1 col j, j>=8 -> y2 col j-8.
__global__ __launch_bounds__(256) void k_proj(const float* __restrict__ x,
                                              const float* __restrict__ W,
                                              float* __restrict__ y1,
                                              float* __restrict__ y2) {
    __shared__ float w[2 * CC * HH];  // 2048 floats
    int tid = threadIdx.x;
    for (int i = tid; i < 2 * CC * HH; i += 256) w[i] = W[i];
    __syncthreads();
    int node = blockIdx.x * 16 + (tid >> 4);
    int j = tid & 15;
    if (node >= NN) return;
    // W row-major [256][8]; rows 0..127 = W1, 128..255 = W2
    int wofs = (j < 8) ? j : (CC * HH + j - 8);
    const float4* xv = (const float4*)(x + (size_t)node * CC);
    float acc = 0.f;
#pragma unroll 4
    for (int k4 = 0; k4 < CC / 4; ++k4) {
        float4 xx = xv[k4];
        int base = k4 * 32 + wofs;  // (k4*4)*8
        acc += xx.x * w[base];
        acc += xx.y * w[base + 8];
        acc += xx.z * w[base + 16];
        acc += xx.w * w[base + 24];
    }
    if (j < 8) y1[(size_t)node * 8 + j] = acc;
    else       y2[(size_t)node * 8 + (j - 8)] = acc;
}

// ---- kernel 2: alpha[e] = lrelu((y1[row]+y2[col]+b)*|ea|)*100 ; atomicMax m[row] ----
__global__ void k_alpha(const int* __restrict__ rowp, const int* __restrict__ colp,
                        const float* __restrict__ ea,
                        const float* __restrict__ y1, const float* __restrict__ y2,
                        const float* __restrict__ bias,
                        float* __restrict__ alpha, unsigned* __restrict__ m) {
    int e = blockIdx.x * blockDim.x + threadIdx.x;
    if (e >= TOT) return;
    int r, c; float wgt;
    if (e < EE) { r = rowp[e]; c = colp[e]; wgt = fabsf(ea[e]); }
    else        { r = e - EE;  c = r;       wgt = 1.0f; }
    const float4* a4 = (const float4*)(y1 + (size_t)r * 8);
    const float4* b4 = (const float4*)(y2 + (size_t)c * 8);
    float va[8], vb[8], bb[8], o[8];
    *(float4*)&va[0] = a4[0]; *(float4*)&va[4] = a4[1];
    *(float4*)&vb[0] = b4[0]; *(float4*)&vb[4] = b4[1];
    *(float4*)&bb[0] = ((const float4*)bias)[0];
    *(float4*)&bb[4] = ((const float4*)bias)[1];
#pragma unroll
    for (int h = 0; h < 8; ++h) {
        float v = (va[h] + vb[h] + bb[h]) * wgt;
        v = (v >= 0.f) ? v : 0.2f * v;   // leaky_relu 0.2
        v *= 100.f;
        o[h] = v;
        atomicMax(&m[(size_t)r * 8 + h], fflip(v));
    }
    float4* o4 = (float4*)(alpha + (size_t)e * 8);
    o4[0] = *(float4*)&o[0]; o4[1] = *(float4*)&o[4];
}

// ---- kernel 3: alpha[e] = exp(alpha[e] - m[row]) ; atomicAdd s[row] ----
__global__ void k_exp(const int* __restrict__ rowp,
                      const unsigned* __restrict__ m,
                      float* __restrict__ alpha, float* __restrict__ s) {
    int e = blockIdx.x * blockDim.x + threadIdx.x;
    if (e >= TOT) return;
    int r = (e < EE) ? rowp[e] : (e - EE);
    float a[8]; unsigned mm[8];
    float4* a4 = (float4*)(alpha + (size_t)e * 8);
    *(float4*)&a[0] = a4[0]; *(float4*)&a[4] = a4[1];
    const uint4* m4 = (const uint4*)(m + (size_t)r * 8);
    *(uint4*)&mm[0] = m4[0]; *(uint4*)&mm[4] = m4[1];
#pragma unroll
    for (int h = 0; h < 8; ++h) {
        float ex = expf(a[h] - funflip(mm[h]));
        a[h] = ex;
        atomicAdd(&s[(size_t)r * 8 + h], ex);
    }
    a4[0] = *(float4*)&a[0]; a4[1] = *(float4*)&a[4];
}

// ---- kernel 4: alpha[e] /= (s[row]+1e-16) ; write row/col as float ----
__global__ void k_norm(const int* __restrict__ rowp, const int* __restrict__ colp,
                       const float* __restrict__ s,
                       float* __restrict__ alpha, float* __restrict__ oidx) {
    int e = blockIdx.x * blockDim.x + threadIdx.x;
    if (e >= TOT) return;
    int r, c;
    if (e < EE) { r = rowp[e]; c = colp[e]; }
    else        { r = e - EE;  c = r; }
    float a[8], ss[8];
    float4* a4 = (float4*)(alpha + (size_t)e * 8);
    *(float4*)&a[0] = a4[0]; *(float4*)&a[4] = a4[1];
    const float4* s4 = (const float4*)(s + (size_t)r * 8);
    *(float4*)&ss[0] = s4[0]; *(float4*)&ss[4] = s4[1];
#pragma unroll
    for (int h = 0; h < 8; ++h) a[h] = a[h] / (ss[h] + 1e-16f);
    a4[0] = *(float4*)&a[0]; a4[1] = *(float4*)&a[4];
    oidx[e] = (float)r;
    oidx[(size_t)TOT + e] = (float)c;
}

extern "C" void kernel_launch(void* const* d_in, const int* in_sizes, int n_in,
                              void* d_out, int out_size, void* d_ws, size_t ws_size,
                              hipStream_t stream) {
    const float* x    = (const float*)d_in[0];
    const int*   rowp = (const int*)d_in[1];          // edge_index[0]
    const int*   colp = rowp + EE;                    // edge_index[1]
    const float* ea   = (const float*)d_in[2];
    const float* W    = (const float*)d_in[3];
    const float* bias = (const float*)d_in[4];

    float* out_alpha = (float*)d_out;                       // [TOT][8]
    float* out_idx   = out_alpha + (size_t)TOT * 8;         // [2][TOT] as float

    // workspace: y1[N*8], y2[N*8], m[N*8] (uint), s[N*8]
    float*    y1 = (float*)d_ws;
    float*    y2 = y1 + (size_t)NN * 8;
    unsigned* m  = (unsigned*)(y2 + (size_t)NN * 8);
    float*    s  = (float*)(m + (size_t)NN * 8);

    const int nm = NN * 8;
    k_init<<<(nm + 255) / 256, 256, 0, stream>>>(m, s, nm);
    k_proj<<<(NN * 16 + 255) / 256, 256, 0, stream>>>(x, W, y1, y2);
    const int blocks = (TOT + 255) / 256;
    k_alpha<<<blocks, 256, 0, stream>>>(rowp, colp, ea, y1, y2, bias, out_alpha, m);
    k_exp<<<blocks, 256, 0, stream>>>(rowp, m, out_alpha, s);
    k_norm<<<blocks, 256, 0, stream>>>(rowp, colp, s, out_alpha, out_idx);
}

// Round 2
// 411.051 us; speedup vs baseline: 3.0081x; 3.0081x over previous
//
#include <hip/hip_runtime.h>

#define NN 50000
#define EE 1600000
#define CC 128
#define HH 8
#define TOT (EE + NN)   // 1,650,000 output rows
#define AVC 16          // LDS-cached chunks per wave: supports deg+1 <= 128

// ---- kernel: y1 = x @ W[:C], y2 = x @ W[C:]  (N x 8 each) ----
__global__ __launch_bounds__(256) void k_proj(const float* __restrict__ x,
                                              const float* __restrict__ W,
                                              float* __restrict__ y1,
                                              float* __restrict__ y2) {
    __shared__ float w[2 * CC * HH];  // 2048 floats
    int tid = threadIdx.x;
    for (int i = tid; i < 2 * CC * HH; i += 256) w[i] = W[i];
    __syncthreads();
    int node = blockIdx.x * 16 + (tid >> 4);
    int j = tid & 15;
    if (node >= NN) return;
    int wofs = (j < 8) ? j : (CC * HH + j - 8);
    const float4* xv = (const float4*)(x + (size_t)node * CC);
    float acc = 0.f;
#pragma unroll 4
    for (int k4 = 0; k4 < CC / 4; ++k4) {
        float4 xx = xv[k4];
        int base = k4 * 32 + wofs;
        acc += xx.x * w[base];
        acc += xx.y * w[base + 8];
        acc += xx.z * w[base + 16];
        acc += xx.w * w[base + 24];
    }
    if (j < 8) y1[(size_t)node * 8 + j] = acc;
    else       y2[(size_t)node * 8 + (j - 8)] = acc;
}

// ---- histogram of edge rows ----
__global__ void k_count(const int* __restrict__ rowp, int* __restrict__ cnt) {
    int e = blockIdx.x * blockDim.x + threadIdx.x;
    if (e < EE) atomicAdd(&cnt[rowp[e]], 1);
}

// ---- single-block exclusive scan: start[0..NN], cur = start copy ----
__global__ __launch_bounds__(1024) void k_scan(const int* __restrict__ cnt,
                                               int* __restrict__ start,
                                               int* __restrict__ cur) {
    __shared__ int part[1024];
    int t = threadIdx.x;
    const int CH = (NN + 1023) / 1024;  // 49
    int lo = t * CH;
    int hi = lo + CH; if (hi > NN) hi = NN;
    int s = 0;
    for (int i = lo; i < hi; ++i) s += cnt[i];
    part[t] = s;
    __syncthreads();
    for (int off = 1; off < 1024; off <<= 1) {
        int v = 0;
        if (t >= off) v = part[t - off];
        __syncthreads();
        if (t >= off) part[t] += v;
        __syncthreads();
    }
    int run = (t == 0) ? 0 : part[t - 1];
    for (int i = lo; i < hi; ++i) {
        start[i] = run;
        cur[i] = run;
        run += cnt[i];
    }
    if (t == 1023) start[NN] = run;   // == EE
}

// ---- scatter edge ids into CSR order ----
__global__ void k_scatter(const int* __restrict__ rowp, int* __restrict__ cur,
                          int* __restrict__ eidx) {
    int e = blockIdx.x * blockDim.x + threadIdx.x;
    if (e < EE) {
        int pos = atomicAdd(&cur[rowp[e]], 1);
        eidx[pos] = e;
    }
}

// ---- index echo output: [row; col] as float ----
__global__ void k_idx(const int* __restrict__ rowp, const int* __restrict__ colp,
                      float* __restrict__ oidx) {
    int e = blockIdx.x * blockDim.x + threadIdx.x;
    if (e >= TOT) return;
    int r, c;
    if (e < EE) { r = rowp[e]; c = colp[e]; }
    else        { r = e - EE;  c = r; }
    oidx[e] = (float)r;
    oidx[(size_t)TOT + e] = (float)c;
}

// ---- alpha for CSR slot i of row r (i == deg -> self loop) ----
__device__ inline float edge_alpha(int i, int deg, int s0, float yh, float y2r,
                                   float bh, int h,
                                   const int* __restrict__ eidx,
                                   const int* __restrict__ colp,
                                   const float* __restrict__ ea,
                                   const float* __restrict__ y2) {
    float z, w;
    if (i < deg) {
        int e = eidx[s0 + i];
        w = fabsf(ea[e]);
        z = yh + y2[(size_t)colp[e] * 8 + h] + bh;
    } else {
        w = 1.0f;
        z = yh + y2r + bh;
    }
    z *= w;
    z = (z >= 0.f) ? z : 0.2f * z;   // leaky_relu 0.2
    return z * 100.f;
}

// ---- fused per-row softmax: one wave per row, final write only ----
__global__ __launch_bounds__(256) void k_row(const int* __restrict__ start,
                                             const int* __restrict__ eidx,
                                             const int* __restrict__ colp,
                                             const float* __restrict__ ea,
                                             const float* __restrict__ y1,
                                             const float* __restrict__ y2,
                                             const float* __restrict__ bias,
                                             float* __restrict__ alpha) {
    __shared__ float av[4][AVC][64];   // 16 KB
    int wv = threadIdx.x >> 6;
    int lane = threadIdx.x & 63;
    int r = blockIdx.x * 4 + wv;
    if (r >= NN) return;
    int sub = lane >> 3;   // edge slot within chunk (0..7)
    int h = lane & 7;      // head
    int s0 = start[r];
    int deg = start[r + 1] - s0;   // real edges
    int tot = deg + 1;             // + self loop
    float yh = y1[(size_t)r * 8 + h];
    float bh = bias[h];
    float y2r = y2[(size_t)r * 8 + h];
    int nch = (tot + 7) >> 3;
    float NEG = -__builtin_inff();

    // pass 1: compute alpha, cache in LDS, running max
    float mx = NEG;
    for (int ch = 0; ch < nch; ++ch) {
        int i = ch * 8 + sub;
        float a = NEG;
        if (i < tot)
            a = edge_alpha(i, deg, s0, yh, y2r, bh, h, eidx, colp, ea, y2);
        if (ch < AVC) av[wv][ch][lane] = a;
        mx = fmaxf(mx, a);
    }
    mx = fmaxf(mx, __shfl_xor(mx, 8, 64));
    mx = fmaxf(mx, __shfl_xor(mx, 16, 64));
    mx = fmaxf(mx, __shfl_xor(mx, 32, 64));

    // pass 2: exp + sum
    float acc = 0.f;
    for (int ch = 0; ch < nch; ++ch) {
        int i = ch * 8 + sub;
        float ex = 0.f;
        if (i < tot) {
            float a = (ch < AVC) ? av[wv][ch][lane]
                    : edge_alpha(i, deg, s0, yh, y2r, bh, h, eidx, colp, ea, y2);
            ex = __expf(a - mx);
        }
        if (ch < AVC) av[wv][ch][lane] = ex;
        acc += ex;
    }
    acc += __shfl_xor(acc, 8, 64);
    acc += __shfl_xor(acc, 16, 64);
    acc += __shfl_xor(acc, 32, 64);
    float inv = 1.0f / (acc + 1e-16f);

    // pass 3: single final write
    for (int ch = 0; ch < nch; ++ch) {
        int i = ch * 8 + sub;
        if (i < tot) {
            float ex;
            if (ch < AVC) ex = av[wv][ch][lane];
            else ex = __expf(edge_alpha(i, deg, s0, yh, y2r, bh, h,
                                        eidx, colp, ea, y2) - mx);
            int opos = (i < deg) ? eidx[s0 + i] : (EE + r);
            alpha[(size_t)opos * 8 + h] = ex * inv;
        }
    }
}

extern "C" void kernel_launch(void* const* d_in, const int* in_sizes, int n_in,
                              void* d_out, int out_size, void* d_ws, size_t ws_size,
                              hipStream_t stream) {
    const float* x    = (const float*)d_in[0];
    const int*   rowp = (const int*)d_in[1];          // edge_index[0]
    const int*   colp = rowp + EE;                    // edge_index[1]
    const float* ea   = (const float*)d_in[2];
    const float* W    = (const float*)d_in[3];
    const float* bias = (const float*)d_in[4];

    float* out_alpha = (float*)d_out;                       // [TOT][8]
    float* out_idx   = out_alpha + (size_t)TOT * 8;         // [2][TOT] as float

    // workspace layout
    float* y1    = (float*)d_ws;                  // NN*8
    float* y2    = y1 + (size_t)NN * 8;           // NN*8
    int*   cnt   = (int*)(y2 + (size_t)NN * 8);   // NN
    int*   start = cnt + NN;                      // NN+1
    int*   cur   = start + NN + 1;                // NN
    int*   eidx  = cur + NN;                      // EE

    hipMemsetAsync(cnt, 0, NN * sizeof(int), stream);
    k_proj<<<(NN * 16 + 255) / 256, 256, 0, stream>>>(x, W, y1, y2);
    k_count<<<(EE + 255) / 256, 256, 0, stream>>>(rowp, cnt);
    k_scan<<<1, 1024, 0, stream>>>(cnt, start, cur);
    k_scatter<<<(EE + 255) / 256, 256, 0, stream>>>(rowp, cur, eidx);
    k_idx<<<(TOT + 255) / 256, 256, 0, stream>>>(rowp, colp, out_idx);
    k_row<<<(NN + 3) / 4, 256, 0, stream>>>(start, eidx, colp, ea, y1, y2,
                                            bias, out_alpha);
}

// Round 3
// 260.157 us; speedup vs baseline: 4.7529x; 1.5800x over previous
//
#include <hip/hip_runtime.h>

#define NN 50000
#define EE 1600000
#define CC 128
#define HH 8
#define TOT (EE + NN)               // 1,650,000 output rows
#define RPB 256                     // rows per bucket
#define NB  ((NN + RPB - 1) / RPB)  // 196 buckets
#define BCH 8192                    // edges per binning block
#define NBB ((EE + BCH - 1) / BCH)  // 196 binning blocks

// ---- monotone float<->uint mapping for atomic max on floats ----
__device__ inline unsigned fflip(float f) {
    unsigned u = __float_as_uint(f);
    return (u & 0x80000000u) ? ~u : (u | 0x80000000u);
}
__device__ inline float funflip(unsigned u) {
    unsigned b = (u & 0x80000000u) ? (u ^ 0x80000000u) : ~u;
    return __uint_as_float(b);
}

// leaky_relu(z,0.2)*100 helper
__device__ inline float act(float z) {
    z = (z >= 0.f) ? z : 0.2f * z;
    return z * 100.f;
}

// ---- y1b = x @ W[:C] + b, y2 = x @ W[C:]  (N x 8 each) ----
__global__ __launch_bounds__(256) void k_proj(const float* __restrict__ x,
                                              const float* __restrict__ W,
                                              const float* __restrict__ bias,
                                              float* __restrict__ y1b,
                                              float* __restrict__ y2) {
    __shared__ float w[2 * CC * HH];  // 2048 floats
    int tid = threadIdx.x;
    for (int i = tid; i < 2 * CC * HH; i += 256) w[i] = W[i];
    __syncthreads();
    int node = blockIdx.x * 16 + (tid >> 4);
    int j = tid & 15;
    if (node >= NN) return;
    int wofs = (j < 8) ? j : (CC * HH + j - 8);
    const float4* xv = (const float4*)(x + (size_t)node * CC);
    float acc = 0.f;
#pragma unroll 4
    for (int k4 = 0; k4 < CC / 4; ++k4) {
        float4 xx = xv[k4];
        int base = k4 * 32 + wofs;
        acc += xx.x * w[base];
        acc += xx.y * w[base + 8];
        acc += xx.z * w[base + 16];
        acc += xx.w * w[base + 24];
    }
    if (j < 8) y1b[(size_t)node * 8 + j] = acc + bias[j];
    else       y2[(size_t)node * 8 + (j - 8)] = acc;
}

// ---- bucket histogram: LDS-aggregated, ~50K global atomics total ----
__global__ __launch_bounds__(1024) void k_hist(const int* __restrict__ rowp,
                                               int* __restrict__ gcnt) {
    __shared__ int h[NB];
    int t = threadIdx.x;
    for (int i = t; i < NB; i += 1024) h[i] = 0;
    __syncthreads();
    int base = blockIdx.x * BCH;
    int n = EE - base; if (n > BCH) n = BCH;
    for (int i = t; i < n; i += 1024)
        atomicAdd(&h[rowp[base + i] >> 8], 1);
    __syncthreads();
    for (int i = t; i < NB; i += 1024)
        if (h[i]) atomicAdd(&gcnt[i], h[i]);
}

// ---- scan of NB bucket counts -> gbase[NB+1], gcur copy ----
__global__ __launch_bounds__(256) void k_scanb(const int* __restrict__ gcnt,
                                               int* __restrict__ gbase,
                                               int* __restrict__ gcur) {
    __shared__ int p[256];
    int t = threadIdx.x;
    int own = (t < NB) ? gcnt[t] : 0;
    p[t] = own;
    __syncthreads();
    for (int off = 1; off < 256; off <<= 1) {
        int v = (t >= off) ? p[t - off] : 0;
        __syncthreads();
        p[t] += v;
        __syncthreads();
    }
    if (t < NB) {
        int ex = p[t] - own;
        gbase[t] = ex;
        gcur[t] = ex;
    }
    if (t == NB - 1) gbase[NB] = p[t];
}

// ---- binning: LDS stage + per-bucket coalesced chunk flush ----
__global__ __launch_bounds__(1024) void k_bin(const int* __restrict__ rowp,
                                              int* __restrict__ gcur,
                                              int* __restrict__ coarse) {
    __shared__ int hist[NB];
    __shared__ int lscan[NB];
    __shared__ int lofs[NB];
    __shared__ int gofs[NB];
    __shared__ int sc[256];
    __shared__ int stage[BCH];
    int t = threadIdx.x;
    int base = blockIdx.x * BCH;
    int n = EE - base; if (n > BCH) n = BCH;
    for (int i = t; i < NB; i += 1024) hist[i] = 0;
    __syncthreads();
    for (int i = t; i < n; i += 1024)
        atomicAdd(&hist[rowp[base + i] >> 8], 1);
    __syncthreads();
    // scan hist (exclusive) over 256-padded entries
    int own = 0;
    if (t < 256) { own = (t < NB) ? hist[t] : 0; sc[t] = own; }
    __syncthreads();
    for (int off = 1; off < 256; off <<= 1) {
        int v = 0;
        if (t < 256 && t >= off) v = sc[t - off];
        __syncthreads();
        if (t < 256 && t >= off) sc[t] += v;
        __syncthreads();
    }
    if (t < NB) {
        int ex = sc[t] - own;
        lscan[t] = ex;
        lofs[t] = ex;
        gofs[t] = own ? atomicAdd(&gcur[t], own) : 0;
    }
    __syncthreads();
    // place edge ids into stage, grouped by bucket
    for (int i = t; i < n; i += 1024) {
        int bkt = rowp[base + i] >> 8;
        int p = atomicAdd(&lofs[bkt], 1);
        stage[p] = base + i;
    }
    __syncthreads();
    // flush: consecutive staged slots of a bucket -> consecutive global slots
    for (int i = t; i < n; i += 1024) {
        int e = stage[i];
        int bkt = rowp[e] >> 8;   // L2-hot gather
        coarse[gofs[bkt] + (i - lscan[bkt])] = e;
    }
}

// ---- per-bucket segment max + sum via LDS atomics -> ms[r][h]=(m,s) ----
__global__ __launch_bounds__(1024) void k_ms(const int* __restrict__ gbase,
                                             const int* __restrict__ coarse,
                                             const int* __restrict__ rowp,
                                             const int* __restrict__ colp,
                                             const float* __restrict__ ea,
                                             const float* __restrict__ y1b,
                                             const float* __restrict__ y2,
                                             float2* __restrict__ ms) {
    __shared__ unsigned mloc[RPB * HH];  // 8 KB
    __shared__ float    sloc[RPB * HH];  // 8 KB
    int b = blockIdx.x;
    int r0 = b * RPB;
    int nr = NN - r0; if (nr > RPB) nr = RPB;
    int t = threadIdx.x;
    // init with self-loop alpha (always present -> no -inf handling)
    for (int i = t; i < nr * HH; i += 1024) {
        int rr = i >> 3, h = i & 7;
        float a = act(y1b[(size_t)(r0 + rr) * 8 + h] + y2[(size_t)(r0 + rr) * 8 + h]);
        mloc[i] = fflip(a);
        sloc[i] = a;              // stash self alpha
    }
    __syncthreads();
    int s0 = gbase[b], s1 = gbase[b + 1];
    // sweep a: max
    for (int i = s0 + t; i < s1; i += 1024) {
        int e = coarse[i];
        int r = rowp[e], c = colp[e];
        float w = fabsf(ea[e]);
        const float4* ya = (const float4*)(y1b + (size_t)r * 8);
        const float4* yb = (const float4*)(y2 + (size_t)c * 8);
        float va[8], vb[8];
        *(float4*)&va[0] = ya[0]; *(float4*)&va[4] = ya[1];
        *(float4*)&vb[0] = yb[0]; *(float4*)&vb[4] = yb[1];
        int lb = (r - r0) * 8;
#pragma unroll
        for (int h = 0; h < 8; ++h)
            atomicMax(&mloc[lb + h], fflip(act((va[h] + vb[h]) * w)));
    }
    __syncthreads();
    // convert self stash -> s init = exp(a_self - m)
    for (int i = t; i < nr * HH; i += 1024)
        sloc[i] = __expf(sloc[i] - funflip(mloc[i]));
    __syncthreads();
    // sweep b: sum of exp
    for (int i = s0 + t; i < s1; i += 1024) {
        int e = coarse[i];
        int r = rowp[e], c = colp[e];
        float w = fabsf(ea[e]);
        const float4* ya = (const float4*)(y1b + (size_t)r * 8);
        const float4* yb = (const float4*)(y2 + (size_t)c * 8);
        float va[8], vb[8];
        *(float4*)&va[0] = ya[0]; *(float4*)&va[4] = ya[1];
        *(float4*)&vb[0] = yb[0]; *(float4*)&vb[4] = yb[1];
        int lb = (r - r0) * 8;
#pragma unroll
        for (int h = 0; h < 8; ++h) {
            float a = act((va[h] + vb[h]) * w);
            atomicAdd(&sloc[lb + h], __expf(a - funflip(mloc[lb + h])));
        }
    }
    __syncthreads();
    for (int i = t; i < nr * HH; i += 1024)
        ms[(size_t)r0 * 8 + i] = make_float2(funflip(mloc[i]), sloc[i]);
}

// ---- edge-parallel finalize: coalesced alpha + index echo ----
__global__ __launch_bounds__(256) void k_final(const int* __restrict__ rowp,
                                               const int* __restrict__ colp,
                                               const float* __restrict__ ea,
                                               const float* __restrict__ y1b,
                                               const float* __restrict__ y2,
                                               const float2* __restrict__ ms,
                                               float* __restrict__ alpha,
                                               float* __restrict__ oidx) {
    int e = blockIdx.x * 256 + threadIdx.x;
    if (e >= TOT) return;
    int r, c; float w;
    if (e < EE) { r = rowp[e]; c = colp[e]; w = fabsf(ea[e]); }
    else        { r = e - EE;  c = r;       w = 1.0f; }
    const float4* ya = (const float4*)(y1b + (size_t)r * 8);
    const float4* yb = (const float4*)(y2 + (size_t)c * 8);
    const float4* mp = (const float4*)(ms + (size_t)r * 8);  // 8 float2
    float va[8], vb[8], mv[16], o[8];
    *(float4*)&va[0] = ya[0]; *(float4*)&va[4] = ya[1];
    *(float4*)&vb[0] = yb[0]; *(float4*)&vb[4] = yb[1];
    *(float4*)&mv[0]  = mp[0]; *(float4*)&mv[4]  = mp[1];
    *(float4*)&mv[8]  = mp[2]; *(float4*)&mv[12] = mp[3];
#pragma unroll
    for (int h = 0; h < 8; ++h) {
        float a = act((va[h] + vb[h]) * w);
        float m = mv[2 * h], s = mv[2 * h + 1];
        o[h] = __expf(a - m) / (s + 1e-16f);
    }
    float4* o4 = (float4*)(alpha + (size_t)e * 8);
    o4[0] = *(float4*)&o[0]; o4[1] = *(float4*)&o[4];
    oidx[e] = (float)r;
    oidx[(size_t)TOT + e] = (float)c;
}

extern "C" void kernel_launch(void* const* d_in, const int* in_sizes, int n_in,
                              void* d_out, int out_size, void* d_ws, size_t ws_size,
                              hipStream_t stream) {
    const float* x    = (const float*)d_in[0];
    const int*   rowp = (const int*)d_in[1];          // edge_index[0]
    const int*   colp = rowp + EE;                    // edge_index[1]
    const float* ea   = (const float*)d_in[2];
    const float* W    = (const float*)d_in[3];
    const float* bias = (const float*)d_in[4];

    float* out_alpha = (float*)d_out;                 // [TOT][8]
    float* out_idx   = out_alpha + (size_t)TOT * 8;   // [2][TOT] as float

    // workspace layout
    float*  y1b    = (float*)d_ws;                    // NN*8
    float*  y2     = y1b + (size_t)NN * 8;            // NN*8
    float2* ms     = (float2*)(y2 + (size_t)NN * 8);  // NN*8 float2
    int*    coarse = (int*)(ms + (size_t)NN * 8);     // EE
    int*    gcnt   = coarse + EE;                     // NB
    int*    gbase  = gcnt + NB;                       // NB+1
    int*    gcur   = gbase + NB + 1;                  // NB

    hipMemsetAsync(gcnt, 0, NB * sizeof(int), stream);
    k_proj<<<(NN * 16 + 255) / 256, 256, 0, stream>>>(x, W, bias, y1b, y2);
    k_hist<<<NBB, 1024, 0, stream>>>(rowp, gcnt);
    k_scanb<<<1, 256, 0, stream>>>(gcnt, gbase, gcur);
    k_bin<<<NBB, 1024, 0, stream>>>(rowp, gcur, coarse);
    k_ms<<<NB, 1024, 0, stream>>>(gbase, coarse, rowp, colp, ea, y1b, y2, ms);
    k_final<<<(TOT + 255) / 256, 256, 0, stream>>>(rowp, colp, ea, y1b, y2, ms,
                                                   out_alpha, out_idx);
}

// Round 4
// 216.315 us; speedup vs baseline: 5.7162x; 1.2027x over previous
//
#include <hip/hip_runtime.h>

#define NN 50000
#define EE 1600000
#define CC 128
#define HH 8
#define TOT (EE + NN)               // 1,650,000 output rows
#define RPB 256                     // rows per bucket
#define NB  ((NN + RPB - 1) / RPB)  // 196 buckets
#define BCH 4096                    // edges per binning block
#define NBB ((EE + BCH - 1) / BCH)  // 391 binning blocks
#define MST 9                       // padded LDS stride (gcd(9,32)=1)

// ---- monotone float<->uint mapping for atomic max on floats ----
__device__ inline unsigned fflip(float f) {
    unsigned u = __float_as_uint(f);
    return (u & 0x80000000u) ? ~u : (u | 0x80000000u);
}
__device__ inline float funflip(unsigned u) {
    unsigned b = (u & 0x80000000u) ? (u ^ 0x80000000u) : ~u;
    return __uint_as_float(b);
}

// leaky_relu(z,0.2)*100
__device__ inline float act(float z) {
    z = (z >= 0.f) ? z : 0.2f * z;
    return z * 100.f;
}

// ---- y1b = x @ W[:C] + b, y2 = x @ W[C:]  (N x 8 each) ----
__global__ __launch_bounds__(256) void k_proj(const float* __restrict__ x,
                                              const float* __restrict__ W,
                                              const float* __restrict__ bias,
                                              float* __restrict__ y1b,
                                              float* __restrict__ y2) {
    __shared__ float w[2 * CC * HH];  // 2048 floats
    int tid = threadIdx.x;
    for (int i = tid; i < 2 * CC * HH; i += 256) w[i] = W[i];
    __syncthreads();
    int node = blockIdx.x * 16 + (tid >> 4);
    int j = tid & 15;
    if (node >= NN) return;
    int wofs = (j < 8) ? j : (CC * HH + j - 8);
    const float4* xv = (const float4*)(x + (size_t)node * CC);
    float acc = 0.f;
#pragma unroll 4
    for (int k4 = 0; k4 < CC / 4; ++k4) {
        float4 xx = xv[k4];
        int base = k4 * 32 + wofs;
        acc += xx.x * w[base];
        acc += xx.y * w[base + 8];
        acc += xx.z * w[base + 16];
        acc += xx.w * w[base + 24];
    }
    if (j < 8) y1b[(size_t)node * 8 + j] = acc + bias[j];
    else       y2[(size_t)node * 8 + (j - 8)] = acc;
}

// ---- bucket histogram: LDS-aggregated ----
__global__ __launch_bounds__(1024) void k_hist(const int* __restrict__ rowp,
                                               int* __restrict__ gcnt) {
    __shared__ int h[NB];
    int t = threadIdx.x;
    for (int i = t; i < NB; i += 1024) h[i] = 0;
    __syncthreads();
    int base = blockIdx.x * BCH;
    int n = EE - base; if (n > BCH) n = BCH;
    for (int i = t; i < n; i += 1024)
        atomicAdd(&h[rowp[base + i] >> 8], 1);
    __syncthreads();
    for (int i = t; i < NB; i += 1024)
        if (h[i]) atomicAdd(&gcnt[i], h[i]);
}

// ---- scan of NB bucket counts -> gbase[NB+1], gcur copy ----
__global__ __launch_bounds__(256) void k_scanb(const int* __restrict__ gcnt,
                                               int* __restrict__ gbase,
                                               int* __restrict__ gcur) {
    __shared__ int p[256];
    int t = threadIdx.x;
    int own = (t < NB) ? gcnt[t] : 0;
    p[t] = own;
    __syncthreads();
    for (int off = 1; off < 256; off <<= 1) {
        int v = (t >= off) ? p[t - off] : 0;
        __syncthreads();
        p[t] += v;
        __syncthreads();
    }
    if (t < NB) {
        int ex = p[t] - own;
        gbase[t] = ex;
        gcur[t] = ex;
    }
    if (t == NB - 1) gbase[NB] = p[t];
}

// ---- binning: pack payload (rloc|col<<8|bkt<<24, |ea|), coalesced flush ----
__global__ __launch_bounds__(1024) void k_bin(const int* __restrict__ rowp,
                                              const int* __restrict__ colp,
                                              const float* __restrict__ ea,
                                              int* __restrict__ gcur,
                                              uint2* __restrict__ pay) {
    __shared__ int hist[NB];
    __shared__ int lscan[NB];
    __shared__ int lofs[NB];
    __shared__ int gofs[NB];
    __shared__ int sc[256];
    __shared__ uint2 stage[BCH];   // 32 KB
    int t = threadIdx.x;
    int base = blockIdx.x * BCH;
    int n = EE - base; if (n > BCH) n = BCH;
    for (int i = t; i < NB; i += 1024) hist[i] = 0;
    __syncthreads();
    for (int i = t; i < n; i += 1024)
        atomicAdd(&hist[rowp[base + i] >> 8], 1);
    __syncthreads();
    int own = 0;
    if (t < 256) { own = (t < NB) ? hist[t] : 0; sc[t] = own; }
    __syncthreads();
    for (int off = 1; off < 256; off <<= 1) {
        int v = 0;
        if (t < 256 && t >= off) v = sc[t - off];
        __syncthreads();
        if (t < 256 && t >= off) sc[t] += v;
        __syncthreads();
    }
    if (t < NB) {
        int ex = sc[t] - own;
        lscan[t] = ex;
        lofs[t] = ex;
        gofs[t] = own ? atomicAdd(&gcur[t], own) : 0;
    }
    __syncthreads();
    // place packed payload into stage, grouped by bucket
    for (int i = t; i < n; i += 1024) {
        int r = rowp[base + i];
        int c = colp[base + i];
        float w = fabsf(ea[base + i]);
        int bkt = r >> 8;
        int p = atomicAdd(&lofs[bkt], 1);
        stage[p] = make_uint2((unsigned)(r & 0xFF) | ((unsigned)c << 8) |
                              ((unsigned)bkt << 24),
                              __float_as_uint(w));
    }
    __syncthreads();
    // flush: consecutive staged slots of a bucket -> consecutive global slots
    for (int i = t; i < n; i += 1024) {
        uint2 v = stage[i];
        int bkt = v.x >> 24;
        pay[gofs[bkt] + (i - lscan[bkt])] = v;
    }
}

// ---- per-bucket segment max + sum via padded LDS atomics ----
__global__ __launch_bounds__(1024) void k_ms(const int* __restrict__ gbase,
                                             const uint2* __restrict__ pay,
                                             const float* __restrict__ y1b,
                                             const float* __restrict__ y2,
                                             float2* __restrict__ ms) {
    __shared__ unsigned mloc[RPB * MST];  // 9.2 KB
    __shared__ float    sloc[RPB * MST];  // 9.2 KB
    __shared__ float    yloc[RPB * MST];  // 9.2 KB (y1b rows, padded)
    int b = blockIdx.x;
    int r0 = b * RPB;
    int nr = NN - r0; if (nr > RPB) nr = RPB;
    int t = threadIdx.x;
    // init with self-loop alpha (always present -> no -inf handling)
    for (int i = t; i < nr * HH; i += 1024) {
        int rr = i >> 3, h = i & 7;
        float yv = y1b[(size_t)r0 * 8 + i];
        float a = act(yv + y2[(size_t)r0 * 8 + i]);   // self: c == r
        int idx = rr * MST + h;
        yloc[idx] = yv;
        mloc[idx] = fflip(a);
        sloc[idx] = a;                                // stash self alpha
    }
    __syncthreads();
    int s0 = gbase[b], s1 = gbase[b + 1];
    // sweep a: max
    for (int i = s0 + t; i < s1; i += 1024) {
        uint2 p = pay[i];
        int rloc = p.x & 0xFF;
        int c = (p.x >> 8) & 0xFFFF;
        float w = __uint_as_float(p.y);
        const float4* yb = (const float4*)(y2 + (size_t)c * 8);
        float vb[8];
        *(float4*)&vb[0] = yb[0]; *(float4*)&vb[4] = yb[1];
        int lb = rloc * MST;
#pragma unroll
        for (int h = 0; h < 8; ++h)
            atomicMax(&mloc[lb + h], fflip(act((yloc[lb + h] + vb[h]) * w)));
    }
    __syncthreads();
    // convert self stash -> s init = exp(a_self - m)
    for (int i = t; i < nr * HH; i += 1024) {
        int idx = (i >> 3) * MST + (i & 7);
        sloc[idx] = __expf(sloc[idx] - funflip(mloc[idx]));
    }
    __syncthreads();
    // sweep b: sum of exp
    for (int i = s0 + t; i < s1; i += 1024) {
        uint2 p = pay[i];
        int rloc = p.x & 0xFF;
        int c = (p.x >> 8) & 0xFFFF;
        float w = __uint_as_float(p.y);
        const float4* yb = (const float4*)(y2 + (size_t)c * 8);
        float vb[8];
        *(float4*)&vb[0] = yb[0]; *(float4*)&vb[4] = yb[1];
        int lb = rloc * MST;
#pragma unroll
        for (int h = 0; h < 8; ++h) {
            float a = act((yloc[lb + h] + vb[h]) * w);
            atomicAdd(&sloc[lb + h], __expf(a - funflip(mloc[lb + h])));
        }
    }
    __syncthreads();
    for (int i = t; i < nr * HH; i += 1024) {
        int idx = (i >> 3) * MST + (i & 7);
        ms[(size_t)r0 * 8 + i] = make_float2(funflip(mloc[idx]), sloc[idx]);
    }
}

// ---- edge-parallel finalize: coalesced alpha + index echo ----
__global__ __launch_bounds__(256) void k_final(const int* __restrict__ rowp,
                                               const int* __restrict__ colp,
                                               const float* __restrict__ ea,
                                               const float* __restrict__ y1b,
                                               const float* __restrict__ y2,
                                               const float2* __restrict__ ms,
                                               float* __restrict__ alpha,
                                               float* __restrict__ oidx) {
    int e = blockIdx.x * 256 + threadIdx.x;
    if (e >= TOT) return;
    int r, c; float w;
    if (e < EE) { r = rowp[e]; c = colp[e]; w = fabsf(ea[e]); }
    else        { r = e - EE;  c = r;       w = 1.0f; }
    const float4* ya = (const float4*)(y1b + (size_t)r * 8);
    const float4* yb = (const float4*)(y2 + (size_t)c * 8);
    const float4* mp = (const float4*)(ms + (size_t)r * 8);  // 8 float2
    float va[8], vb[8], mv[16], o[8];
    *(float4*)&va[0] = ya[0]; *(float4*)&va[4] = ya[1];
    *(float4*)&vb[0] = yb[0]; *(float4*)&vb[4] = yb[1];
    *(float4*)&mv[0]  = mp[0]; *(float4*)&mv[4]  = mp[1];
    *(float4*)&mv[8]  = mp[2]; *(float4*)&mv[12] = mp[3];
#pragma unroll
    for (int h = 0; h < 8; ++h) {
        float a = act((va[h] + vb[h]) * w);
        float m = mv[2 * h], s = mv[2 * h + 1];
        o[h] = __expf(a - m) / (s + 1e-16f);
    }
    float4* o4 = (float4*)(alpha + (size_t)e * 8);
    o4[0] = *(float4*)&o[0]; o4[1] = *(float4*)&o[4];
    oidx[e] = (float)r;
    oidx[(size_t)TOT + e] = (float)c;
}

extern "C" void kernel_launch(void* const* d_in, const int* in_sizes, int n_in,
                              void* d_out, int out_size, void* d_ws, size_t ws_size,
                              hipStream_t stream) {
    const float* x    = (const float*)d_in[0];
    const int*   rowp = (const int*)d_in[1];          // edge_index[0]
    const int*   colp = rowp + EE;                    // edge_index[1]
    const float* ea   = (const float*)d_in[2];
    const float* W    = (const float*)d_in[3];
    const float* bias = (const float*)d_in[4];

    float* out_alpha = (float*)d_out;                 // [TOT][8]
    float* out_idx   = out_alpha + (size_t)TOT * 8;   // [2][TOT] as float

    // workspace layout
    float*  y1b   = (float*)d_ws;                     // NN*8
    float*  y2    = y1b + (size_t)NN * 8;             // NN*8
    float2* ms    = (float2*)(y2 + (size_t)NN * 8);   // NN*8 float2
    uint2*  pay   = (uint2*)(ms + (size_t)NN * 8);    // EE uint2 (12.8 MB)
    int*    gcnt  = (int*)(pay + (size_t)EE);         // NB
    int*    gbase = gcnt + NB;                        // NB+1
    int*    gcur  = gbase + NB + 1;                   // NB

    hipMemsetAsync(gcnt, 0, NB * sizeof(int), stream);
    k_proj<<<(NN * 16 + 255) / 256, 256, 0, stream>>>(x, W, bias, y1b, y2);
    k_hist<<<NBB, 1024, 0, stream>>>(rowp, gcnt);
    k_scanb<<<1, 256, 0, stream>>>(gcnt, gbase, gcur);
    k_bin<<<NBB, 1024, 0, stream>>>(rowp, colp, ea, gcur, pay);
    k_ms<<<NB, 1024, 0, stream>>>(gbase, pay, y1b, y2, ms);
    k_final<<<(TOT + 255) / 256, 256, 0, stream>>>(rowp, colp, ea, y1b, y2, ms,
                                                   out_alpha, out_idx);
}